// Round 1
// baseline (433.963 us; speedup 1.0000x reference)
//
#include <hip/hip_runtime.h>

#define HH 1200
#define WW 1920
#define HW (HH*WW)
#define MINC (1.0f/1048575.0f)
#define LOGMC (-13.862942657524135f)
#define CROP_N 576000   // 600 rows (1,3,..,1199) x 960 cols (0,2,..,1918)

// ---- workspace layout (bytes) ----
#define O_COARSE 0                 // u32[4096]
#define O_FINE   16384             // u32[256]
#define O_HIST   17408             // u32[256]
#define O_ROWSEL 18432             // u8[1200]
#define O_COLSEL 19712             // u8[1920]
#define O_INTS   21632             // i32: [0]=k, [1]=T, [2]=kprime
#define O_SCALE  21648             // f32 scale
#define O_A1     21696             // f32[8192]
#define O_A2     54464             // f32[4096]
#define O_A3     70848             // f32[2048]
#define O_A4     79040             // f32[1024]
#define O_A5     83136             // f32[16]
#define WS_TOTAL 83200

__device__ __forceinline__ float merge3(float low, float mid, float high) {
    float lm = (mid == 4095.0f) ? low : 0.0f;
    float hm = (mid <= 255.0f) ? high : 0.0f;
    float mm = (mid >= 256.0f && mid <= 4094.0f) ? mid : 0.0f;
    return hm * (1.0f/256.0f) + mm * (1.0f/16.0f) + lm;
}

// K1: build row/col selection masks + k (single block)
__global__ void k_setup(unsigned char* rowsel, unsigned char* colsel, int* ints) {
    __shared__ unsigned char rmask[HH];
    __shared__ unsigned char cmask[WW];
    __shared__ int cnts[2];
    int t = threadIdx.x;
    for (int i = t; i < HH; i += 256) rmask[i] = 0;
    for (int i = t; i < WW; i += 256) cmask[i] = 0;
    if (t < 2) cnts[t] = 0;
    __syncthreads();
    for (int p = t; p < 21*25; p += 256) {
        int by = p / 25, ty = p % 25;
        int base = (int)(by * (1200.0 / 42.0));
        int y = (ty + 4 + base) << 1;
        if (y < HH) rmask[y] = 1;
    }
    for (int p = t; p < 21*40; p += 256) {
        int bx = p / 40, tx = p % 40;
        int base = (int)(bx * (1920.0 / 42.0));
        int x = (tx + 5 + base) << 1;
        if (x < WW) cmask[x] = 1;
    }
    __syncthreads();
    for (int i = t; i < HH; i += 256) {
        int iy = i * (HH - 4) / HH;
        unsigned char v = rmask[iy + 4];
        rowsel[i] = v;
        if (v) atomicAdd(&cnts[0], 1);
    }
    for (int i = t; i < WW; i += 256) {
        int ix = i * (WW - 4) / WW;
        unsigned char v = cmask[ix + 4];
        colsel[i] = v;
        if (v) atomicAdd(&cnts[1], 1);
    }
    __syncthreads();
    if (t == 0) {
        long long n = (long long)cnts[0] * (long long)cnts[1];
        long long k = n >> 1;
        if (k < 1) k = 1;
        ints[0] = (int)k;
    }
}

// K2: coarse 4096-bin histogram of q>>8 over selected pixels (batch 0)
__global__ void k_coarse(const float* __restrict__ img,
                         const unsigned char* __restrict__ rowsel,
                         const unsigned char* __restrict__ colsel,
                         unsigned int* coarse) {
    int idx = blockIdx.x * blockDim.x + threadIdx.x;
    if (idx >= HW) return;
    int y = idx / WW;
    int x = idx - y * WW;
    if (!rowsel[y] || !colsel[x]) return;
    float low  = rintf(img[idx] * 4095.0f);
    float mid  = rintf(img[idx + HW] * 4095.0f);
    float high = rintf(img[idx + 2*HW] * 4095.0f);
    float v = merge3(low, mid, high);
    int q = __float2int_rn(v * 256.0f);   // exact: v is multiple of 1/256
    atomicAdd(&coarse[q >> 8], 1u);
}

// K3: find target coarse bin T and residual rank kprime (1 block, 1024 thr)
__global__ void k_coarsesel(const unsigned int* __restrict__ coarse, int* ints) {
    __shared__ unsigned int part[1024];
    int t = threadIdx.x;
    unsigned int b0 = coarse[t*4], b1 = coarse[t*4+1], b2 = coarse[t*4+2], b3 = coarse[t*4+3];
    unsigned int s = b0 + b1 + b2 + b3;
    part[t] = s;
    __syncthreads();
    for (int off = 1; off < 1024; off <<= 1) {
        unsigned int v = (t >= off) ? part[t - off] : 0u;
        __syncthreads();
        part[t] += v;
        __syncthreads();
    }
    unsigned int incl = part[t];
    unsigned int excl = incl - s;
    unsigned int k = (unsigned int)ints[0];
    if (excl < k && k <= incl) {
        unsigned int bs[4] = {b0, b1, b2, b3};
        unsigned int cum = excl;
        for (int i = 0; i < 4; i++) {
            if (cum + bs[i] >= k) { ints[1] = t*4 + i; ints[2] = (int)(k - cum); break; }
            cum += bs[i];
        }
    }
}

// K4: fine 256-bin histogram within coarse bin T
__global__ void k_fine(const float* __restrict__ img,
                       const unsigned char* __restrict__ rowsel,
                       const unsigned char* __restrict__ colsel,
                       const int* __restrict__ ints,
                       unsigned int* fine) {
    int idx = blockIdx.x * blockDim.x + threadIdx.x;
    if (idx >= HW) return;
    int y = idx / WW;
    int x = idx - y * WW;
    if (!rowsel[y] || !colsel[x]) return;
    float low  = rintf(img[idx] * 4095.0f);
    float mid  = rintf(img[idx + HW] * 4095.0f);
    float high = rintf(img[idx + 2*HW] * 4095.0f);
    float v = merge3(low, mid, high);
    int q = __float2int_rn(v * 256.0f);
    if ((q >> 8) == ints[1]) atomicAdd(&fine[q & 255], 1u);
}

// K5: exact median -> scale
__global__ void k_select(const unsigned int* __restrict__ fine, const int* __restrict__ ints,
                         float* scale_p) {
    if (threadIdx.x != 0) return;
    int kprime = ints[2];
    int T = ints[1];
    unsigned int cum = 0;
    int j = 0;
    for (; j < 256; j++) { cum += fine[j]; if ((int)cum >= kprime) break; }
    if (j > 255) j = 255;
    float median = fmaxf((float)(T*256 + j) * (1.0f/256.0f), MINC);
    *scale_p = 1.0f / (1024.0f * median);
}

// K6: crop-0 histogram (rows 1:1200:2, cols 0:1920:2)
__global__ void k_crophist(const float* __restrict__ img, const float* __restrict__ scale_p,
                           unsigned int* hist) {
    __shared__ unsigned int lh[256];
    int t = threadIdx.x;
    lh[t] = 0;
    __syncthreads();
    float scale = *scale_p;
    int base = blockIdx.x * (256*16);
    for (int i = 0; i < 16; i++) {
        int p = base + i*256 + t;
        if (p < CROP_N) {
            int pr = p / 960;
            int py = 1 + 2*pr;
            int px = 2*(p - pr*960);
            int idx = py * WW + px;
            float low  = rintf(img[idx] * 4095.0f);
            float mid  = rintf(img[idx + HW] * 4095.0f);
            float high = rintf(img[idx + 2*HW] * 4095.0f);
            float v = merge3(low, mid, high);
            float mv = fminf(v * scale, 1.0f);
            mv = fmaxf(mv, MINC);
            float tt = (LOGMC - logf(mv)) / LOGMC;
            int b = (int)(tt * 256.0f);
            if (b < 0) b = 0;
            if (b > 255) b = 255;
            atomicAdd(&lh[b], 1u);
        }
    }
    __syncthreads();
    if (lh[t]) atomicAdd(&hist[t], lh[t]);
}

// L1: (1,1,256,1)->(128,64): out[oc,r] = relu(b1 + sum_kh h[4r+kh]*w1[oc,kh])
__global__ void k_l1(const unsigned int* __restrict__ hist, const float* __restrict__ w1,
                     const float* __restrict__ b1, float* a1) {
    int t = blockIdx.x * blockDim.x + threadIdx.x;
    if (t >= 128*64) return;
    int oc = t >> 6, r = t & 63;
    float acc = b1[oc];
    for (int kh = 0; kh < 4; kh++) {
        float h = ((float)hist[4*r + kh] / 576000.0f) * 256.0f;
        acc += h * w1[oc*4 + kh];
    }
    a1[t] = fmaxf(acc, 0.0f);
}

// L2: (128,64)->(256,16)
__global__ void k_l2(const float* __restrict__ a1, const float* __restrict__ w2,
                     const float* __restrict__ b2, float* a2) {
    int t = blockIdx.x * blockDim.x + threadIdx.x;
    if (t >= 256*16) return;
    int oc = t >> 4, r = t & 15;
    float acc = b2[oc];
    const float* wp = w2 + oc*128*4;
    for (int ic = 0; ic < 128; ic++) {
        const float* ap = a1 + ic*64 + 4*r;
        acc += ap[0]*wp[ic*4+0] + ap[1]*wp[ic*4+1] + ap[2]*wp[ic*4+2] + ap[3]*wp[ic*4+3];
    }
    a2[t] = fmaxf(acc, 0.0f);
}

// L3: (256,16)->(512,4)
__global__ void k_l3(const float* __restrict__ a2, const float* __restrict__ w3,
                     const float* __restrict__ b3, float* a3) {
    int t = blockIdx.x * blockDim.x + threadIdx.x;
    if (t >= 512*4) return;
    int oc = t >> 2, r = t & 3;
    float acc = b3[oc];
    const float* wp = w3 + oc*256*4;
    for (int ic = 0; ic < 256; ic++) {
        const float* ap = a2 + ic*16 + 4*r;
        acc += ap[0]*wp[ic*4+0] + ap[1]*wp[ic*4+1] + ap[2]*wp[ic*4+2] + ap[3]*wp[ic*4+3];
    }
    a3[t] = fmaxf(acc, 0.0f);
}

// L4: (512,4)->(1024,1)
__global__ void k_l4(const float* __restrict__ a3, const float* __restrict__ w4,
                     const float* __restrict__ b4, float* a4) {
    int t = blockIdx.x * blockDim.x + threadIdx.x;
    if (t >= 1024) return;
    float acc = b4[t];
    const float* wp = w4 + t*512*4;
    for (int ic = 0; ic < 512; ic++) {
        const float* ap = a3 + ic*4;
        acc += ap[0]*wp[ic*4+0] + ap[1]*wp[ic*4+1] + ap[2]*wp[ic*4+2] + ap[3]*wp[ic*4+3];
    }
    a4[t] = fmaxf(acc, 0.0f);
}

// L5: 1024 -> 16
__global__ void k_l5(const float* __restrict__ a4, const float* __restrict__ w5,
                     const float* __restrict__ b5, float* a5) {
    int t = threadIdx.x;
    if (t >= 16) return;
    float acc = b5[t];
    const float* wp = w5 + t*1024;
    for (int ic = 0; ic < 1024; ic++) acc += a4[ic] * wp[ic];
    a5[t] = fmaxf(acc, 0.0f);
}

// L6 + sigmoid/exp epilogue -> single output scalar
__global__ void k_l6(const float* __restrict__ a5, const float* __restrict__ w6,
                     const float* __restrict__ b6, float* out) {
    if (threadIdx.x != 0) return;
    float o = b6[0];
    for (int ic = 0; ic < 16; ic++) o += a5[ic] * w6[ic];
    float s = 1.0f / (1.0f + expf(-3.0f * o));
    float y = 2.0f * (s - 0.5f);
    y = y * 1.3862943611198906f;  // log(4)
    out[0] = expf(y);
}

extern "C" void kernel_launch(void* const* d_in, const int* in_sizes, int n_in,
                              void* d_out, int out_size, void* d_ws, size_t ws_size,
                              hipStream_t stream) {
    const float* img = (const float*)d_in[0];   // (4,3,1200,1920) f32 — only batch 0 used
    const float* w1 = (const float*)d_in[1];
    const float* b1 = (const float*)d_in[2];
    const float* w2 = (const float*)d_in[3];
    const float* b2 = (const float*)d_in[4];
    const float* w3 = (const float*)d_in[5];
    const float* b3 = (const float*)d_in[6];
    const float* w4 = (const float*)d_in[7];
    const float* b4 = (const float*)d_in[8];
    const float* w5 = (const float*)d_in[9];
    const float* b5 = (const float*)d_in[10];
    const float* w6 = (const float*)d_in[11];
    const float* b6 = (const float*)d_in[12];
    float* out = (float*)d_out;

    char* ws = (char*)d_ws;
    unsigned int* coarse = (unsigned int*)(ws + O_COARSE);
    unsigned int* fine   = (unsigned int*)(ws + O_FINE);
    unsigned int* hist   = (unsigned int*)(ws + O_HIST);
    unsigned char* rowsel = (unsigned char*)(ws + O_ROWSEL);
    unsigned char* colsel = (unsigned char*)(ws + O_COLSEL);
    int* ints   = (int*)(ws + O_INTS);
    float* scale_p = (float*)(ws + O_SCALE);
    float* a1 = (float*)(ws + O_A1);
    float* a2 = (float*)(ws + O_A2);
    float* a3 = (float*)(ws + O_A3);
    float* a4 = (float*)(ws + O_A4);
    float* a5 = (float*)(ws + O_A5);

    hipMemsetAsync(d_ws, 0, WS_TOTAL, stream);

    k_setup<<<1, 256, 0, stream>>>(rowsel, colsel, ints);
    k_coarse<<<HW/256, 256, 0, stream>>>(img, rowsel, colsel, coarse);
    k_coarsesel<<<1, 1024, 0, stream>>>(coarse, ints);
    k_fine<<<HW/256, 256, 0, stream>>>(img, rowsel, colsel, ints, fine);
    k_select<<<1, 64, 0, stream>>>(fine, ints, scale_p);
    k_crophist<<<(CROP_N + 4095)/4096, 256, 0, stream>>>(img, scale_p, hist);
    k_l1<<<32, 256, 0, stream>>>(hist, w1, b1, a1);
    k_l2<<<16, 256, 0, stream>>>(a1, w2, b2, a2);
    k_l3<<<8, 256, 0, stream>>>(a2, w3, b3, a3);
    k_l4<<<4, 256, 0, stream>>>(a3, w4, b4, a4);
    k_l5<<<1, 64, 0, stream>>>(a4, w5, b5, a5);
    k_l6<<<1, 64, 0, stream>>>(a5, w6, b6, out);
}

// Round 2
// 71.189 us; speedup vs baseline: 6.0960x; 6.0960x over previous
//
#include <hip/hip_runtime.h>

#define HH 1200
#define WW 1920
#define HW (HH*WW)
#define MINC (1.0f/1048575.0f)
#define LOGMC (-13.862942657524135f)
#define CROP_N 576000   // 600 rows (1,3,..,1199) x 960 cols (0,2,..,1918)

// ---- workspace layout (bytes) ----
#define O_COARSE 0          // u32[4096]
#define O_FINE   16384      // u32[256]
#define O_HIST   17408      // u32[256]
#define O_ROWIDX 18432      // i32[600]
#define O_COLIDX 20864      // i32[960]
#define O_INTS   24704      // i32[8]: 0=k 1=T 2=kprime 3=nr 4=nc
#define O_A2     24768      // f32[4096]
#define O_A3     41152      // f32[2048]
#define O_A4     49344      // f32[1024]
#define WS_TOTAL 53440
#define ZERO_BYTES 18432    // coarse+fine+hist must be zeroed every call

__device__ __forceinline__ float merge3(float low, float mid, float high) {
    float lm = (mid == 4095.0f) ? low : 0.0f;
    float hm = (mid <= 255.0f) ? high : 0.0f;
    float mm = (mid >= 256.0f && mid <= 4094.0f) ? mid : 0.0f;
    return hm * (1.0f/256.0f) + mm * (1.0f/16.0f) + lm;
}

__device__ __forceinline__ int merged_q(const float* img, int idx) {
    float low  = rintf(img[idx] * 4095.0f);
    float mid  = rintf(img[idx + HW] * 4095.0f);
    float high = rintf(img[idx + 2*HW] * 4095.0f);
    float v = merge3(low, mid, high);
    return __float2int_rn(v * 256.0f);   // exact: v is a multiple of 1/256
}

// K1: build compacted row/col index lists + k (single block).
// Order of idx lists is irrelevant (histogram/median over a multiset).
__global__ void k_setup(int* rowidx, int* colidx, int* ints) {
    __shared__ unsigned char rmask[HH];
    __shared__ unsigned char cmask[WW];
    __shared__ int s_nr, s_nc;
    int t = threadIdx.x;
    for (int i = t; i < HH; i += 256) rmask[i] = 0;
    for (int i = t; i < WW; i += 256) cmask[i] = 0;
    if (t == 0) { s_nr = 0; s_nc = 0; }
    __syncthreads();
    for (int p = t; p < 21*25; p += 256) {
        int by = p / 25, ty = p % 25;
        int base = (int)(by * (1200.0 / 42.0));
        int y = (ty + 4 + base) << 1;
        if (y < HH) rmask[y] = 1;
    }
    for (int p = t; p < 21*40; p += 256) {
        int bx = p / 40, tx = p % 40;
        int base = (int)(bx * (1920.0 / 42.0));
        int x = (tx + 5 + base) << 1;
        if (x < WW) cmask[x] = 1;
    }
    __syncthreads();
    for (int i = t; i < HH; i += 256) {
        int iy = i * (HH - 4) / HH;
        if (rmask[iy + 4]) { int pos = atomicAdd(&s_nr, 1); rowidx[pos] = i; }
    }
    for (int i = t; i < WW; i += 256) {
        int ix = i * (WW - 4) / WW;
        if (cmask[ix + 4]) { int pos = atomicAdd(&s_nc, 1); colidx[pos] = i; }
    }
    __syncthreads();
    if (t == 0) {
        ints[3] = s_nr;
        ints[4] = s_nc;
        long long n = (long long)s_nr * (long long)s_nc;
        long long k = n >> 1;
        if (k < 1) k = 1;
        ints[0] = (int)k;
    }
}

// K2: coarse 4096-bin histogram over selected pixels, LDS-privatized
__global__ void k_coarse(const float* __restrict__ img,
                         const int* __restrict__ rowidx,
                         const int* __restrict__ colidx,
                         const int* __restrict__ ints,
                         unsigned int* coarse) {
    __shared__ unsigned int lh[4096];
    int t = threadIdx.x;
    for (int i = t; i < 4096; i += 256) lh[i] = 0;
    __syncthreads();
    int nr = ints[3], nc = ints[4];
    int total = nr * nc;
    int stride = gridDim.x * blockDim.x;
    for (int p = blockIdx.x * 256 + t; p < total; p += stride) {
        int r = p / nc, c = p - r * nc;
        int idx = rowidx[r] * WW + colidx[c];
        int q = merged_q(img, idx);
        atomicAdd(&lh[q >> 8], 1u);
    }
    __syncthreads();
    for (int i = t; i < 4096; i += 256) {
        unsigned int v = lh[i];
        if (v) atomicAdd(&coarse[i], v);
    }
}

// K3: find target coarse bin T and residual rank kprime (1 block, 1024 thr)
__global__ void k_coarsesel(const unsigned int* __restrict__ coarse, int* ints) {
    __shared__ unsigned int part[1024];
    int t = threadIdx.x;
    unsigned int b0 = coarse[t*4], b1 = coarse[t*4+1], b2 = coarse[t*4+2], b3 = coarse[t*4+3];
    unsigned int s = b0 + b1 + b2 + b3;
    part[t] = s;
    __syncthreads();
    for (int off = 1; off < 1024; off <<= 1) {
        unsigned int v = (t >= off) ? part[t - off] : 0u;
        __syncthreads();
        part[t] += v;
        __syncthreads();
    }
    unsigned int incl = part[t];
    unsigned int excl = incl - s;
    unsigned int k = (unsigned int)ints[0];
    if (excl < k && k <= incl) {
        unsigned int bs[4] = {b0, b1, b2, b3};
        unsigned int cum = excl;
        for (int i = 0; i < 4; i++) {
            if (cum + bs[i] >= k) { ints[1] = t*4 + i; ints[2] = (int)(k - cum); break; }
            cum += bs[i];
        }
    }
}

// K4: fine 256-bin histogram within coarse bin T, LDS-privatized
__global__ void k_fine(const float* __restrict__ img,
                       const int* __restrict__ rowidx,
                       const int* __restrict__ colidx,
                       const int* __restrict__ ints,
                       unsigned int* fine) {
    __shared__ unsigned int lh[256];
    int t = threadIdx.x;
    lh[t] = 0;
    __syncthreads();
    int nr = ints[3], nc = ints[4], T = ints[1];
    int total = nr * nc;
    int stride = gridDim.x * blockDim.x;
    for (int p = blockIdx.x * 256 + t; p < total; p += stride) {
        int r = p / nc, c = p - r * nc;
        int idx = rowidx[r] * WW + colidx[c];
        int q = merged_q(img, idx);
        if ((q >> 8) == T) atomicAdd(&lh[q & 255], 1u);
    }
    __syncthreads();
    if (lh[t]) atomicAdd(&fine[t], lh[t]);
}

// K5: crop-0 histogram; median-select fused in (every block redoes the tiny scan)
#define CROP_PPT 8   // pixels per thread
__global__ void k_crophist(const float* __restrict__ img,
                           const unsigned int* __restrict__ fine,
                           const int* __restrict__ ints,
                           unsigned int* hist) {
    __shared__ unsigned int lh[256];
    __shared__ unsigned int sf[256];
    __shared__ float s_scale;
    int t = threadIdx.x;
    lh[t] = 0;
    sf[t] = fine[t];
    __syncthreads();
    if (t == 0) {
        int kprime = ints[2];
        int T = ints[1];
        unsigned int cum = 0;
        int j = 0;
        for (; j < 256; j++) { cum += sf[j]; if ((int)cum >= kprime) break; }
        if (j > 255) j = 255;
        float median = fmaxf((float)(T*256 + j) * (1.0f/256.0f), MINC);
        s_scale = 1.0f / (1024.0f * median);
    }
    __syncthreads();
    float scale = s_scale;
    int base = blockIdx.x * (256*CROP_PPT);
    for (int i = 0; i < CROP_PPT; i++) {
        int p = base + i*256 + t;
        if (p < CROP_N) {
            int pr = p / 960;
            int py = 1 + 2*pr;
            int px = 2*(p - pr*960);
            int idx = py * WW + px;
            float low  = rintf(img[idx] * 4095.0f);
            float mid  = rintf(img[idx + HW] * 4095.0f);
            float high = rintf(img[idx + 2*HW] * 4095.0f);
            float v = merge3(low, mid, high);
            float mv = fminf(v * scale, 1.0f);
            mv = fmaxf(mv, MINC);
            float tt = (LOGMC - logf(mv)) / LOGMC;
            int b = (int)(tt * 256.0f);
            if (b < 0) b = 0;
            if (b > 255) b = 255;
            atomicAdd(&lh[b], 1u);
        }
    }
    __syncthreads();
    if (lh[t]) atomicAdd(&hist[t], lh[t]);
}

// L1+L2 fused: a1 (128x64) computed into LDS per block, then L2 -> a2 (256x16)
__global__ void k_l12(const unsigned int* __restrict__ hist,
                      const float* __restrict__ w1, const float* __restrict__ b1,
                      const float* __restrict__ w2, const float* __restrict__ b2,
                      float* a2) {
    __shared__ float sa1[8192];   // 32 KB
    int t = threadIdx.x;
    for (int j = t; j < 8192; j += 256) {
        int oc = j >> 6, r = j & 63;
        float acc = b1[oc];
        for (int kh = 0; kh < 4; kh++) {
            float h = ((float)hist[4*r + kh] / 576000.0f) * 256.0f;
            acc += h * w1[oc*4 + kh];
        }
        sa1[j] = fmaxf(acc, 0.0f);
    }
    __syncthreads();
    int o = blockIdx.x * 256 + t;     // 0..4095
    int oc = o >> 4, r = o & 15;
    float acc = b2[oc];
    const float* wp = w2 + oc*128*4;
    for (int ic = 0; ic < 128; ic++) {
        const float* ap = sa1 + ic*64 + 4*r;
        acc += ap[0]*wp[ic*4+0] + ap[1]*wp[ic*4+1] + ap[2]*wp[ic*4+2] + ap[3]*wp[ic*4+3];
    }
    a2[o] = fmaxf(acc, 0.0f);
}

// L3: 512 blocks (one per oc), 256 threads; a2 staged in LDS; 4 outputs/block
__global__ void k_l3(const float* __restrict__ a2, const float* __restrict__ w3,
                     const float* __restrict__ b3, float* a3) {
    __shared__ float sa2[4096];
    int t = threadIdx.x;
    int oc = blockIdx.x;
    for (int i = t; i < 4096; i += 256) sa2[i] = a2[i];
    __syncthreads();
    int r = t >> 6, lane = t & 63;
    const float* wp = w3 + oc*1024;
    float p = 0.0f;
    for (int ii = 0; ii < 4; ii++) {
        int ic = lane + 64*ii;
        const float* ap = sa2 + ic*16 + 4*r;
        const float* w = wp + ic*4;
        p += ap[0]*w[0] + ap[1]*w[1] + ap[2]*w[2] + ap[3]*w[3];
    }
    for (int off = 32; off > 0; off >>= 1) p += __shfl_down(p, off, 64);
    if (lane == 0) a3[oc*4 + r] = fmaxf(p + b3[oc], 0.0f);
}

// L4: 1024 blocks (one per oc), 256 threads; dot of length 2048
__global__ void k_l4(const float* __restrict__ a3, const float* __restrict__ w4,
                     const float* __restrict__ b4, float* a4) {
    __shared__ float red[4];
    int t = threadIdx.x;
    int oc = blockIdx.x;
    const float* wp = w4 + oc*2048;
    float p = 0.0f;
    for (int i = 0; i < 8; i++) {
        int m = t + 256*i;
        p += a3[m] * wp[m];
    }
    for (int off = 32; off > 0; off >>= 1) p += __shfl_down(p, off, 64);
    int lane = t & 63;
    if (lane == 0) red[t >> 6] = p;
    __syncthreads();
    if (t == 0) a4[oc] = fmaxf(red[0]+red[1]+red[2]+red[3] + b4[oc], 0.0f);
}

// L5+L6 fused: 1 block, 1024 threads (16 waves, one per L5 output) + epilogue
__global__ void k_l56(const float* __restrict__ a4,
                      const float* __restrict__ w5, const float* __restrict__ b5,
                      const float* __restrict__ w6, const float* __restrict__ b6,
                      float* out) {
    __shared__ float sa5[16];
    int t = threadIdx.x;
    int w = t >> 6, lane = t & 63;
    const float* wp = w5 + w*1024;
    float p = 0.0f;
    for (int i = 0; i < 16; i++) {
        int ic = lane + 64*i;
        p += a4[ic] * wp[ic];
    }
    for (int off = 32; off > 0; off >>= 1) p += __shfl_down(p, off, 64);
    if (lane == 0) sa5[w] = fmaxf(p + b5[w], 0.0f);
    __syncthreads();
    if (t == 0) {
        float o = b6[0];
        for (int ic = 0; ic < 16; ic++) o += sa5[ic] * w6[ic];
        float s = 1.0f / (1.0f + expf(-3.0f * o));
        float y = 2.0f * (s - 0.5f) * 1.3862943611198906f;  // log(4)
        out[0] = expf(y);
    }
}

extern "C" void kernel_launch(void* const* d_in, const int* in_sizes, int n_in,
                              void* d_out, int out_size, void* d_ws, size_t ws_size,
                              hipStream_t stream) {
    const float* img = (const float*)d_in[0];   // (4,3,1200,1920) f32 — only batch 0 matters
    const float* w1 = (const float*)d_in[1];
    const float* b1 = (const float*)d_in[2];
    const float* w2 = (const float*)d_in[3];
    const float* b2 = (const float*)d_in[4];
    const float* w3 = (const float*)d_in[5];
    const float* b3 = (const float*)d_in[6];
    const float* w4 = (const float*)d_in[7];
    const float* b4 = (const float*)d_in[8];
    const float* w5 = (const float*)d_in[9];
    const float* b5 = (const float*)d_in[10];
    const float* w6 = (const float*)d_in[11];
    const float* b6 = (const float*)d_in[12];
    float* out = (float*)d_out;

    char* ws = (char*)d_ws;
    unsigned int* coarse = (unsigned int*)(ws + O_COARSE);
    unsigned int* fine   = (unsigned int*)(ws + O_FINE);
    unsigned int* hist   = (unsigned int*)(ws + O_HIST);
    int* rowidx = (int*)(ws + O_ROWIDX);
    int* colidx = (int*)(ws + O_COLIDX);
    int* ints   = (int*)(ws + O_INTS);
    float* a2 = (float*)(ws + O_A2);
    float* a3 = (float*)(ws + O_A3);
    float* a4 = (float*)(ws + O_A4);

    hipMemsetAsync(d_ws, 0, ZERO_BYTES, stream);

    k_setup<<<1, 256, 0, stream>>>(rowidx, colidx, ints);
    k_coarse<<<256, 256, 0, stream>>>(img, rowidx, colidx, ints, coarse);
    k_coarsesel<<<1, 1024, 0, stream>>>(coarse, ints);
    k_fine<<<256, 256, 0, stream>>>(img, rowidx, colidx, ints, fine);
    k_crophist<<<(CROP_N + 256*CROP_PPT - 1)/(256*CROP_PPT), 256, 0, stream>>>(img, fine, ints, hist);
    k_l12<<<16, 256, 0, stream>>>(hist, w1, b1, w2, b2, a2);
    k_l3<<<512, 256, 0, stream>>>(a2, w3, b3, a3);
    k_l4<<<1024, 256, 0, stream>>>(a3, w4, b4, a4);
    k_l56<<<1, 1024, 0, stream>>>(a4, w5, b5, w6, b6, out);
}